// Round 12
// baseline (229.708 us; speedup 1.0000x reference)
//
#include <hip/hip_runtime.h>
#include <hip/hip_bf16.h>

// S=2048, B=2, E=1024, H=16, hd=64. fp32 I/O, bf16 MFMA internal.
// Pipeline: prep (rope table + W->bf16 + X->bf16)
//   -> qkv_gemm (128x128, BK=64, global_load_lds + XOR-swizzled LDS,
//      table-RoPE epilogue, Q pre-scaled by 0.125*log2e, V pre-transposed)
//   -> flash attn (8 waves x 16 q-rows, K-tile 128, exp2 softmax,
//      REGISTER-PREFETCH double-buffered staging)
//   -> out_gemm (128x128, BK=64, in-kernel Wo cvt).
//
// Lessons encoded: r5 (no dynamic acc/reg indexing), r8 (LDS staging is the
// latency hider), r10 (attn tracks waves/CU; keep 16 q-rows/wave).
//
// Memory plan:
//   d_out (16 MB fp32):
//     [0 .. 8MB):   bf16 K head-major during attention (dead before out_gemm)
//     [8 ..14MB):   bf16 Wq|Wk|Wv (dead after qkv_gemm)
//     [14..14.5MB): fp32 RoPE table [2048][64] (cos | sin halves)
//   ws[0 .. 8MB):  Vt = V transposed [bh][d][s] bf16
//   ws[8 ..16MB):  Q head-major [bh][s][d] bf16; attn O overwrites Q in-place.
//   ws[16..24MB):  Xb = X as bf16 (plan A, ws_size >= 24 MB; else fallback).

typedef short shortx8 __attribute__((ext_vector_type(8)));
typedef float floatx4 __attribute__((ext_vector_type(4)));

#define S_LEN 2048
#define BATCH 2
#define EMB 1024
#define NH 16
#define HD 64
#define BH 32
#define MROWS 4096
#define HEAD_STRIDE (S_LEN*HD)  // 131072

// Q projection scale: hd^-0.5 * log2(e)  (softmax uses exp2; identical math)
#define QSCALE 0.1803368801111204f

#if __has_builtin(__builtin_amdgcn_exp2f)
#define EXP2(x) __builtin_amdgcn_exp2f(x)
#else
#define EXP2(x) exp2f(x)
#endif

__device__ __forceinline__ float b2f(unsigned short u) {
    union { unsigned int i; float f; } v; v.i = ((unsigned int)u) << 16; return v.f;
}
__device__ __forceinline__ unsigned short f2b(float f) {
    union { float f; unsigned int i; } v; v.f = f;
    unsigned int x = v.i;
    return (unsigned short)((x + 0x7fffu + ((x >> 16) & 1u)) >> 16);
}
// round-half-up bf16: 2 VALU ops; max 1/2-ULP error. Verified harmless (r8-r11).
__device__ __forceinline__ unsigned short f2b_fast(float f) {
    union { float f; unsigned int i; } v; v.f = f;
    return (unsigned short)((v.i + 0x8000u) >> 16);
}
__device__ __forceinline__ shortx8 cvt8(const float* p) {
    floatx4 a = *(const floatx4*)p;
    floatx4 b = *(const floatx4*)(p + 4);
    shortx8 r;
    r[0] = (short)f2b(a[0]); r[1] = (short)f2b(a[1]);
    r[2] = (short)f2b(a[2]); r[3] = (short)f2b(a[3]);
    r[4] = (short)f2b(b[0]); r[5] = (short)f2b(b[1]);
    r[6] = (short)f2b(b[2]); r[7] = (short)f2b(b[3]);
    return r;
}
// async global->LDS, 16B per lane; LDS dest must be wave-uniform base + lane*16
__device__ __forceinline__ void g2l16(const unsigned short* g, unsigned short* l) {
    __builtin_amdgcn_global_load_lds(
        (const __attribute__((address_space(1))) unsigned int*)(const void*)g,
        (__attribute__((address_space(3))) unsigned int*)(void*)l, 16, 0, 0);
}

// ---------------------------------------------------------------------------
// prep: segment-partitioned grid (no intra-block divergence):
//   [0,65536): RoPE table; [65536,458752): W cvt; [458752,983040): X cvt.
// ---------------------------------------------------------------------------
__global__ __launch_bounds__(256) void prep(
    const float* __restrict__ X,
    const float* __restrict__ Wq, const float* __restrict__ Wk,
    const float* __restrict__ Wv,
    unsigned short* __restrict__ Xb, unsigned short* __restrict__ Wb,
    float* __restrict__ rtab)
{
    const int g = blockIdx.x * 256 + threadIdx.x;
    if (g < 65536) {
        const int s = g >> 5, j = g & 31;
        const float inv = expf(-(float)j * (9.210340371976184f / 32.0f));
        const float ang = (float)s * inv;
        rtab[s * 64 + j]      = cosf(ang);
        rtab[s * 64 + 32 + j] = sinf(ang);
    } else if (g < 458752) {
        const int h = g - 65536;
        const int seg = h >> 17;
        const int idx = (h & 131071) * 8;
        const float* W = (seg == 0) ? Wq : (seg == 1) ? Wk : Wv;
        *(shortx8*)&Wb[seg * 1048576 + idx] = cvt8(&W[idx]);
    } else {
        const int idx = (g - 458752) * 8;       // < 4194304
        *(shortx8*)&Xb[idx] = cvt8(&X[idx]);
    }
}

// ---------------------------------------------------------------------------
// Shared epilogue for qkv: bias, Q-scale(+log2e), table-RoPE, scatter bf16.
// Q/K head-major [bh][s][d]; V TRANSPOSED [bh][d][s]. Fully unrolled.
// ---------------------------------------------------------------------------
__device__ __forceinline__ void qkv_epilogue(
    floatx4 (&acc)[4][4], int mat, int m0, int nn0, int wm, int wn,
    int qm, int quad, const float* bias, const float* rtab,
    unsigned short* dst)
{
    if (mat == 2) {
#pragma unroll
        for (int i = 0; i < 4; i++) {
#pragma unroll
            for (int j = 0; j < 4; j++) {
                const int colg = nn0 + wn + j * 16 + qm;
                const float bv_ = bias[colg];
                const int h = colg >> 6, d = colg & 63;
#pragma unroll
                for (int r = 0; r < 4; r++) {
                    const int rowg = m0 + wm + i * 16 + quad * 4 + r;  // s*2+b
                    const int s = rowg >> 1, b = rowg & 1;
                    dst[((b * NH + h) * HD + d) * S_LEN + s] = f2b(acc[i][j][r] + bv_);
                }
            }
        }
    } else {
        const float scale = (mat == 0) ? QSCALE : 1.0f;
#pragma unroll
        for (int i = 0; i < 4; i++) {
#pragma unroll
            for (int jp = 0; jp < 2; jp++) {
                const int c1 = nn0 + wn + jp * 16 + qm;        // col of low half
                const float b1 = bias[c1], b2 = bias[c1 + 32];
                const int h = c1 >> 6;
                const int d1 = c1 & 63;                        // = jp*16+qm, < 32
#pragma unroll
                for (int r = 0; r < 4; r++) {
                    const int rowg = m0 + wm + i * 16 + quad * 4 + r;  // s*2+b
                    const int s = rowg >> 1, b = rowg & 1;
                    const float cs = rtab[s * 64 + d1];
                    const float sn = rtab[s * 64 + d1 + 32];
                    const float x1 = (acc[i][jp][r] + b1) * scale;
                    const float x2 = (acc[i][jp + 2][r] + b2) * scale;
                    unsigned short* base = &dst[((b * NH + h) * S_LEN + s) * HD];
                    base[d1]      = f2b(x1 * cs - x2 * sn);
                    base[d1 + 32] = f2b(x2 * cs + x1 * sn);
                }
            }
        }
    }
}

// ---------------------------------------------------------------------------
// QKV projection, plan A (frozen r10/r11): global_load_lds staging,
// unpadded LDS [128][64] with XOR column swizzle.
// ---------------------------------------------------------------------------
__global__ __launch_bounds__(256) void qkv_gemm_gl(
    const unsigned short* __restrict__ Xb,
    const unsigned short* __restrict__ Wb,   // Wq|Wk|Wv bf16, 1M elems each
    const float* __restrict__ bq, const float* __restrict__ bk,
    const float* __restrict__ bv,
    const float* __restrict__ rtab,
    unsigned short* __restrict__ Qh, unsigned short* __restrict__ Kh,
    unsigned short* __restrict__ Vt)
{
    __shared__ unsigned short At[128 * 64];   // 16 KB, unpadded
    __shared__ unsigned short Bt[128 * 64];   // 16 KB, unpadded

    const int tid  = threadIdx.x;
    const int wave = tid >> 6, lane = tid & 63;
    const int wm = (wave >> 1) * 64, wn = (wave & 1) * 64;
    const int qm = lane & 15, quad = lane >> 4;

    const int m0  = blockIdx.x * 128;
    const int n0g = blockIdx.y * 128;
    const int mat = n0g >> 10;              // 0=q 1=k 2=v
    const int nn0 = n0g & 1023;

    const unsigned short* W = Wb + (size_t)mat * 1048576;
    const float* bias = (mat == 0) ? bq : (mat == 1) ? bk : bv;
    unsigned short* dst = (mat == 0) ? Qh : (mat == 1) ? Kh : Vt;

    floatx4 acc[4][4] = {};

    const int xs = qm & 7;   // reader xor term: row&7 == qm&7 for frag rows

    for (int k0 = 0; k0 < EMB; k0 += 64) {
#pragma unroll
        for (int c = 0; c < 4; c++) {
            const int e   = (c * 256 + tid) * 8;          // LDS elem offset
            const int row = e >> 6;                       // 0..127
            const int gcol = (((e >> 3) & 7) ^ (row & 7)) * 8;
            g2l16(&Xb[(m0 + row) * EMB + k0 + gcol], &At[e]);
            g2l16(&W[(nn0 + row) * EMB + k0 + gcol], &Bt[e]);
        }
        __syncthreads();

#pragma unroll
        for (int kk = 0; kk < 2; kk++) {
            shortx8 a[4], b[4];
#pragma unroll
            for (int i = 0; i < 4; i++)
                a[i] = *(shortx8*)&At[(wm + i * 16 + qm) * 64 + (((kk * 4 + quad) ^ xs) * 8)];
#pragma unroll
            for (int j = 0; j < 4; j++)
                b[j] = *(shortx8*)&Bt[(wn + j * 16 + qm) * 64 + (((kk * 4 + quad) ^ xs) * 8)];
#pragma unroll
            for (int i = 0; i < 4; i++)
#pragma unroll
                for (int j = 0; j < 4; j++)
                    acc[i][j] = __builtin_amdgcn_mfma_f32_16x16x32_bf16(a[i], b[j], acc[i][j], 0, 0, 0);
        }
        __syncthreads();
    }

    qkv_epilogue(acc, mat, m0, nn0, wm, wn, qm, quad, bias, rtab, dst);
}

// ---------------------------------------------------------------------------
// QKV projection, plan B fallback (r7 structure, padded LDS, in-kernel X cvt).
// ---------------------------------------------------------------------------
#define LDB 72

__global__ __launch_bounds__(256) void qkv_gemm_fb(
    const float* __restrict__ X,
    const unsigned short* __restrict__ Wb,
    const float* __restrict__ bq, const float* __restrict__ bk,
    const float* __restrict__ bv,
    const float* __restrict__ rtab,
    unsigned short* __restrict__ Qh, unsigned short* __restrict__ Kh,
    unsigned short* __restrict__ Vt)
{
    __shared__ unsigned short At[128 * LDB];
    __shared__ unsigned short Bt[128 * LDB];

    const int tid  = threadIdx.x;
    const int wave = tid >> 6, lane = tid & 63;
    const int wm = (wave >> 1) * 64, wn = (wave & 1) * 64;
    const int qm = lane & 15, quad = lane >> 4;

    const int m0  = blockIdx.x * 128;
    const int n0g = blockIdx.y * 128;
    const int mat = n0g >> 10;
    const int nn0 = n0g & 1023;

    const unsigned short* W = Wb + (size_t)mat * 1048576;
    const float* bias = (mat == 0) ? bq : (mat == 1) ? bk : bv;
    unsigned short* dst = (mat == 0) ? Qh : (mat == 1) ? Kh : Vt;

    const int r0 = tid >> 3;
    const int ko = (tid & 7) * 8;

    floatx4 acc[4][4] = {};

    for (int k0 = 0; k0 < EMB; k0 += 64) {
#pragma unroll
        for (int c = 0; c < 4; c++) {
            const int row = r0 + 32 * c;
            *(shortx8*)&At[row * LDB + ko] = cvt8(&X[(m0 + row) * EMB + k0 + ko]);
            *(shortx8*)&Bt[row * LDB + ko] = *(const shortx8*)&W[(nn0 + row) * EMB + k0 + ko];
        }
        __syncthreads();

#pragma unroll
        for (int kk = 0; kk < 2; kk++) {
            shortx8 a[4], b[4];
#pragma unroll
            for (int i = 0; i < 4; i++)
                a[i] = *(shortx8*)&At[(wm + i * 16 + qm) * LDB + kk * 32 + quad * 8];
#pragma unroll
            for (int j = 0; j < 4; j++)
                b[j] = *(shortx8*)&Bt[(wn + j * 16 + qm) * LDB + kk * 32 + quad * 8];
#pragma unroll
            for (int i = 0; i < 4; i++)
#pragma unroll
                for (int j = 0; j < 4; j++)
                    acc[i][j] = __builtin_amdgcn_mfma_f32_16x16x32_bf16(a[i], b[j], acc[i][j], 0, 0, 0);
        }
        __syncthreads();
    }

    qkv_epilogue(acc, mat, m0, nn0, wm, wn, qm, quad, bias, rtab, dst);
}

// ---------------------------------------------------------------------------
// Flash attention v6: r11 shape (8 waves x 16 q-rows, K-tile 128, 512 blocks)
// + REGISTER-PREFETCH double buffering: tile kt+1's global loads issue right
// after the head barrier and land during tile kt's compute, so the barrier
// drain only waits on cheap ds_writes, never on HBM/L2 latency.
// Two explicit register buffers, loop unrolled x2 (static indexing only).
// ---------------------------------------------------------------------------
#define LDK 72    // K rows: 64 d + pad
#define LDV 136   // VT/P rows: 128 s + pad

__device__ __forceinline__ void attn_tile_compute(
    const unsigned short* ldsK, const unsigned short* ldsVT,
    unsigned short* myP, shortx8 aq0, shortx8 aq1,
    int qm, int quad, floatx4 (&od)[4], float (&l_part)[4])
{
    floatx4 sc[8];
#pragma unroll
    for (int nt = 0; nt < 8; nt++) {
        const int krow = nt * 16 + qm;
        const shortx8 b0 = *(const shortx8*)&ldsK[krow * LDK + quad * 8];
        const shortx8 b1 = *(const shortx8*)&ldsK[krow * LDK + 32 + quad * 8];
        floatx4 a = {};
        a = __builtin_amdgcn_mfma_f32_16x16x32_bf16(aq0, b0, a, 0, 0, 0);
        a = __builtin_amdgcn_mfma_f32_16x16x32_bf16(aq1, b1, a, 0, 0, 0);
        sc[nt] = a;
    }
#pragma unroll
    for (int nt = 0; nt < 8; nt++)
#pragma unroll
        for (int r = 0; r < 4; r++)
            sc[nt][r] = EXP2(sc[nt][r]);
#pragma unroll
    for (int r = 0; r < 4; r++) {
        float t0 = (sc[0][r] + sc[1][r]) + (sc[2][r] + sc[3][r]);
        float t1 = (sc[4][r] + sc[5][r]) + (sc[6][r] + sc[7][r]);
        l_part[r] += t0 + t1;
    }
#pragma unroll
    for (int nt = 0; nt < 8; nt++)
#pragma unroll
        for (int r = 0; r < 4; r++)
            myP[(quad * 4 + r) * LDV + nt * 16 + qm] = f2b_fast(sc[nt][r]);

    shortx8 ap[4];
#pragma unroll
    for (int kc = 0; kc < 4; kc++)
        ap[kc] = *(const shortx8*)&myP[qm * LDV + kc * 32 + quad * 8];
#pragma unroll
    for (int dt = 0; dt < 4; dt++) {
        const int d = dt * 16 + qm;
#pragma unroll
        for (int kc = 0; kc < 4; kc++) {
            const shortx8 vb = *(const shortx8*)&ldsVT[d * LDV + kc * 32 + quad * 8];
            od[dt] = __builtin_amdgcn_mfma_f32_16x16x32_bf16(ap[kc], vb, od[dt], 0, 0, 0);
        }
    }
}

__global__ __launch_bounds__(512) void attn_kernel(
    unsigned short* Qh,               // read, then overwritten in-place with O
    const unsigned short* __restrict__ Kh,
    const unsigned short* __restrict__ Vt)
{
    __shared__ unsigned short ldsK[128 * LDK];      // 18432 B
    __shared__ unsigned short ldsVT[64 * LDV];      // 17408 B
    __shared__ unsigned short ldsP[8 * 16 * LDV];   // 34816 B

    const int tid  = threadIdx.x;
    const int wave = tid >> 6, lane = tid & 63;     // wave 0..7
    const int qm = lane & 15, quad = lane >> 4;
    const int bh = blockIdx.y;
    const int qrow = blockIdx.x * 128 + wave * 16;

    unsigned short* Qp = Qh + bh * HEAD_STRIDE;
    const unsigned short* Kp = Kh + bh * HEAD_STRIDE;
    const unsigned short* Vp = Vt + bh * HEAD_STRIDE;   // [d][s]

    const shortx8 aq0 = *(const shortx8*)&Qp[(qrow + qm) * HD + quad * 8];
    const shortx8 aq1 = *(const shortx8*)&Qp[(qrow + qm) * HD + 32 + quad * 8];

    floatx4 od[4] = {};
    float l_part[4] = {0.f, 0.f, 0.f, 0.f};

    unsigned short* myP = &ldsP[wave * 16 * LDV];

    const int kr = tid >> 3;        // 0..63
    const int ko = (tid & 7) * 8;   // 0..56
    const int vr = tid >> 4;        // 0..31
    const int vo = (tid & 15) * 8;  // 0..120

    // register double-buffers (static names only -- r5 lesson)
    shortx8 ka0, ka1, va0, va1;     // buffer A
    shortx8 kb0, kb1, vb0, vb1;     // buffer B

    // preload tile 0 into A
    ka0 = *(const shortx8*)&Kp[kr * HD + ko];
    ka1 = *(const shortx8*)&Kp[(kr + 64) * HD + ko];
    va0 = *(const shortx8*)&Vp[vr * S_LEN + vo];
    va1 = *(const shortx8*)&Vp[(vr + 32) * S_LEN + vo];

    for (int kt = 0; kt < S_LEN / 128; kt += 2) {
        // ---- even iter: LDS <- buffer A; prefetch kt+1 into B ----
        *(shortx8*)&ldsK[kr * LDK + ko]         = ka0;
        *(shortx8*)&ldsK[(kr + 64) * LDK + ko]  = ka1;
        *(shortx8*)&ldsVT[vr * LDV + vo]        = va0;
        *(shortx8*)&ldsVT[(vr + 32) * LDV + vo] = va1;
        __syncthreads();
        {
            const int kb = (kt + 1) * 128;
            kb0 = *(const shortx8*)&Kp[(kb + kr) * HD + ko];
            kb1 = *(const shortx8*)&Kp[(kb + kr + 64) * HD + ko];
            vb0 = *(const shortx8*)&Vp[vr * S_LEN + kb + vo];
            vb1 = *(const shortx8*)&Vp[(vr + 32) * S_LEN + kb + vo];
        }
        attn_tile_compute(ldsK, ldsVT, myP, aq0, aq1, qm, quad, od, l_part);
        __syncthreads();

        // ---- odd iter: LDS <- buffer B; prefetch kt+2 into A ----
        *(shortx8*)&ldsK[kr * LDK + ko]         = kb0;
        *(shortx8*)&ldsK[(kr + 64) * LDK + ko]  = kb1;
        *(shortx8*)&ldsVT[vr * LDV + vo]        = vb0;
        *(shortx8*)&ldsVT[(vr + 32) * LDV + vo] = vb1;
        __syncthreads();
        if (kt + 2 < S_LEN / 128) {
            const int kb = (kt + 2) * 128;
            ka0 = *(const shortx8*)&Kp[(kb + kr) * HD + ko];
            ka1 = *(const shortx8*)&Kp[(kb + kr + 64) * HD + ko];
            va0 = *(const shortx8*)&Vp[vr * S_LEN + kb + vo];
            va1 = *(const shortx8*)&Vp[(vr + 32) * S_LEN + kb + vo];
        }
        attn_tile_compute(ldsK, ldsVT, myP, aq0, aq1, qm, quad, od, l_part);
        __syncthreads();
    }

    float inv_l[4];
#pragma unroll
    for (int r = 0; r < 4; r++) {
        float s = l_part[r];
        for (int off = 1; off < 16; off <<= 1) s += __shfl_xor(s, off, 64);
        inv_l[r] = 1.0f / s;
    }

#pragma unroll
    for (int r = 0; r < 4; r++) {
        const int rq = qrow + quad * 4 + r;
#pragma unroll
        for (int dt = 0; dt < 4; dt++) {
            const int d = dt * 16 + qm;
            Qp[rq * HD + d] = f2b(od[dt][r] * inv_l[r]);
        }
    }
}

// ---------------------------------------------------------------------------
// Output projection v2: out = O[4096,1024] @ Wo^T + bo (fp32 out).
// 128x128 tile, BK=64 (16 iters); Wo converted fp32->bf16 during staging
// (cvt_w1 kernel deleted). O bf16 head-major.
// ---------------------------------------------------------------------------
__global__ __launch_bounds__(256) void out_gemm(
    const unsigned short* __restrict__ O,
    const float* __restrict__ Wo, const float* __restrict__ bo,
    float* __restrict__ out)
{
    __shared__ unsigned short At[128 * LDB];
    __shared__ unsigned short Bt[128 * LDB];

    const int tid  = threadIdx.x;
    const int wave = tid >> 6, lane = tid & 63;
    const int wm = (wave >> 1) * 64, wn = (wave & 1) * 64;
    const int qm = lane & 15, quad = lane >> 4;
    const int m0 = blockIdx.x * 128;
    const int n0 = blockIdx.y * 128;

    const int r0 = tid >> 3;          // 0..31
    const int ko = (tid & 7) * 8;     // 0..56

    floatx4 acc[4][4] = {};

    for (int k0 = 0; k0 < EMB; k0 += 64) {
        const int k = k0 + ko;
#pragma unroll
        for (int c = 0; c < 4; c++) {
            const int row = r0 + 32 * c;
            const int m = m0 + row;
            // head-major gather: 8 contiguous elems stay within one head
            *(shortx8*)&At[row * LDB + ko] =
                *(const shortx8*)&O[(((m & 1) * NH + (k >> 6)) * S_LEN + (m >> 1)) * HD + (k & 63)];
            *(shortx8*)&Bt[row * LDB + ko] = cvt8(&Wo[(n0 + row) * EMB + k]);
        }
        __syncthreads();

#pragma unroll
        for (int kk = 0; kk < 2; kk++) {
            shortx8 a[4], b[4];
#pragma unroll
            for (int i = 0; i < 4; i++)
                a[i] = *(shortx8*)&At[(wm + i * 16 + qm) * LDB + kk * 32 + quad * 8];
#pragma unroll
            for (int j = 0; j < 4; j++)
                b[j] = *(shortx8*)&Bt[(wn + j * 16 + qm) * LDB + kk * 32 + quad * 8];
#pragma unroll
            for (int i = 0; i < 4; i++)
#pragma unroll
                for (int j = 0; j < 4; j++)
                    acc[i][j] = __builtin_amdgcn_mfma_f32_16x16x32_bf16(a[i], b[j], acc[i][j], 0, 0, 0);
        }
        __syncthreads();
    }

#pragma unroll
    for (int i = 0; i < 4; i++) {
#pragma unroll
        for (int j = 0; j < 4; j++) {
            const int colg = n0 + wn + j * 16 + qm;
            const float bv_ = bo[colg];
#pragma unroll
            for (int r = 0; r < 4; r++) {
                const int rowg = m0 + wm + i * 16 + quad * 4 + r;
                out[rowg * EMB + colg] = acc[i][j][r] + bv_;
            }
        }
    }
}

// ---------------------------------------------------------------------------
extern "C" void kernel_launch(void* const* d_in, const int* in_sizes, int n_in,
                              void* d_out, int out_size, void* d_ws, size_t ws_size,
                              hipStream_t stream) {
    const float* X  = (const float*)d_in[0];
    const float* Wq = (const float*)d_in[1];
    const float* bq = (const float*)d_in[2];
    const float* Wk = (const float*)d_in[3];
    const float* bk = (const float*)d_in[4];
    const float* Wv = (const float*)d_in[5];
    const float* bv = (const float*)d_in[6];
    const float* Wo = (const float*)d_in[7];
    const float* bo = (const float*)d_in[8];
    float* out = (float*)d_out;

    unsigned short* ws = (unsigned short*)d_ws;
    unsigned short* Vt  = ws;                                  // [32][64][2048] bf16
    unsigned short* Qh  = ws + (size_t)BH * HEAD_STRIDE;       // [32][2048][64] bf16
    unsigned short* Xb  = ws + (size_t)2 * BH * HEAD_STRIDE;   // [4096][1024] bf16 (plan A)
    unsigned short* Kh  = (unsigned short*)d_out;              // [0..4M) u16 (borrowed)
    unsigned short* Wb  = (unsigned short*)d_out + 4194304;    // [4M..7M) u16: Wq|Wk|Wv bf16
    float*          Rt  = (float*)d_out + 3670016;             // [14..14.5MB): rope table

    const bool use_xb = ws_size >= (size_t)24 * 1024 * 1024;   // constant per session

    prep<<<dim3(use_xb ? 3840 : 1792), 256, 0, stream>>>(X, Wq, Wk, Wv, Xb, Wb, Rt);

    if (use_xb)
        qkv_gemm_gl<<<dim3(MROWS / 128, 3 * EMB / 128), 256, 0, stream>>>(
            Xb, Wb, bq, bk, bv, Rt, Qh, Kh, Vt);
    else
        qkv_gemm_fb<<<dim3(MROWS / 128, 3 * EMB / 128), 256, 0, stream>>>(
            X, Wb, bq, bk, bv, Rt, Qh, Kh, Vt);

    attn_kernel<<<dim3(S_LEN / 128, BH), 512, 0, stream>>>(Qh, Kh, Vt);
    out_gemm<<<dim3(MROWS / 128, EMB / 128), 256, 0, stream>>>(Qh, Wo, bo, out);
}

// Round 13
// 223.580 us; speedup vs baseline: 1.0274x; 1.0274x over previous
//
#include <hip/hip_runtime.h>
#include <hip/hip_bf16.h>

// S=2048, B=2, E=1024, H=16, hd=64. fp32 I/O, bf16 MFMA internal.
// Pipeline: prep (rope table + W->bf16 + X->bf16)
//   -> qkv_gemm (128x128, BK=64, global_load_lds + XOR-swizzled LDS,
//      table-RoPE epilogue, Q pre-scaled by 0.125*log2e, V pre-transposed)
//   -> flash attn (r11 exact: 8 waves x 16 q-rows, K-tile 128, exp2 softmax)
//   -> out_gemm (128x128, BK=64, in-kernel Wo cvt).
//
// Lessons encoded: r5 (no dynamic acc/reg indexing), r8 (LDS staging is the
// latency hider), r10 (attn tracks waves/CU), r12 (explicit register
// prefetch on the 2-barrier loop costs occupancy and regresses; attn is
// LDS-BW-bound, ~2.5 GB of fragment reads / 78.6 TB/s ~= 32 us floor).
//
// Memory plan:
//   d_out (16 MB fp32):
//     [0 .. 8MB):   bf16 K head-major during attention (dead before out_gemm)
//     [8 ..14MB):   bf16 Wq|Wk|Wv (dead after qkv_gemm)
//     [14..14.5MB): fp32 RoPE table [2048][64] (cos | sin halves)
//   ws[0 .. 8MB):  Vt = V transposed [bh][d][s] bf16
//   ws[8 ..16MB):  Q head-major [bh][s][d] bf16; attn O overwrites Q in-place.
//   ws[16..24MB):  Xb = X as bf16 (plan A, ws_size >= 24 MB; else fallback).

typedef short shortx8 __attribute__((ext_vector_type(8)));
typedef float floatx4 __attribute__((ext_vector_type(4)));

#define S_LEN 2048
#define BATCH 2
#define EMB 1024
#define NH 16
#define HD 64
#define BH 32
#define MROWS 4096
#define HEAD_STRIDE (S_LEN*HD)  // 131072

// Q projection scale: hd^-0.5 * log2(e)  (softmax uses exp2; identical math)
#define QSCALE 0.1803368801111204f

#if __has_builtin(__builtin_amdgcn_exp2f)
#define EXP2(x) __builtin_amdgcn_exp2f(x)
#else
#define EXP2(x) exp2f(x)
#endif

__device__ __forceinline__ float b2f(unsigned short u) {
    union { unsigned int i; float f; } v; v.i = ((unsigned int)u) << 16; return v.f;
}
__device__ __forceinline__ unsigned short f2b(float f) {
    union { float f; unsigned int i; } v; v.f = f;
    unsigned int x = v.i;
    return (unsigned short)((x + 0x7fffu + ((x >> 16) & 1u)) >> 16);
}
// round-half-up bf16: 2 VALU ops; max 1/2-ULP error. Verified harmless (r8-r12).
__device__ __forceinline__ unsigned short f2b_fast(float f) {
    union { float f; unsigned int i; } v; v.f = f;
    return (unsigned short)((v.i + 0x8000u) >> 16);
}
__device__ __forceinline__ shortx8 cvt8(const float* p) {
    floatx4 a = *(const floatx4*)p;
    floatx4 b = *(const floatx4*)(p + 4);
    shortx8 r;
    r[0] = (short)f2b(a[0]); r[1] = (short)f2b(a[1]);
    r[2] = (short)f2b(a[2]); r[3] = (short)f2b(a[3]);
    r[4] = (short)f2b(b[0]); r[5] = (short)f2b(b[1]);
    r[6] = (short)f2b(b[2]); r[7] = (short)f2b(b[3]);
    return r;
}
// async global->LDS, 16B per lane; LDS dest must be wave-uniform base + lane*16
__device__ __forceinline__ void g2l16(const unsigned short* g, unsigned short* l) {
    __builtin_amdgcn_global_load_lds(
        (const __attribute__((address_space(1))) unsigned int*)(const void*)g,
        (__attribute__((address_space(3))) unsigned int*)(void*)l, 16, 0, 0);
}

// ---------------------------------------------------------------------------
// prep: segment-partitioned grid (no intra-block divergence):
//   [0,65536): RoPE table; [65536,458752): W cvt; [458752,983040): X cvt.
// ---------------------------------------------------------------------------
__global__ __launch_bounds__(256) void prep(
    const float* __restrict__ X,
    const float* __restrict__ Wq, const float* __restrict__ Wk,
    const float* __restrict__ Wv,
    unsigned short* __restrict__ Xb, unsigned short* __restrict__ Wb,
    float* __restrict__ rtab)
{
    const int g = blockIdx.x * 256 + threadIdx.x;
    if (g < 65536) {
        const int s = g >> 5, j = g & 31;
        const float inv = expf(-(float)j * (9.210340371976184f / 32.0f));
        const float ang = (float)s * inv;
        rtab[s * 64 + j]      = cosf(ang);
        rtab[s * 64 + 32 + j] = sinf(ang);
    } else if (g < 458752) {
        const int h = g - 65536;
        const int seg = h >> 17;
        const int idx = (h & 131071) * 8;
        const float* W = (seg == 0) ? Wq : (seg == 1) ? Wk : Wv;
        *(shortx8*)&Wb[seg * 1048576 + idx] = cvt8(&W[idx]);
    } else {
        const int idx = (g - 458752) * 8;       // < 4194304
        *(shortx8*)&Xb[idx] = cvt8(&X[idx]);
    }
}

// ---------------------------------------------------------------------------
// Shared epilogue for qkv: bias, Q-scale(+log2e), table-RoPE, scatter bf16.
// Q/K head-major [bh][s][d]; V TRANSPOSED [bh][d][s]. Fully unrolled.
// ---------------------------------------------------------------------------
__device__ __forceinline__ void qkv_epilogue(
    floatx4 (&acc)[4][4], int mat, int m0, int nn0, int wm, int wn,
    int qm, int quad, const float* bias, const float* rtab,
    unsigned short* dst)
{
    if (mat == 2) {
#pragma unroll
        for (int i = 0; i < 4; i++) {
#pragma unroll
            for (int j = 0; j < 4; j++) {
                const int colg = nn0 + wn + j * 16 + qm;
                const float bv_ = bias[colg];
                const int h = colg >> 6, d = colg & 63;
#pragma unroll
                for (int r = 0; r < 4; r++) {
                    const int rowg = m0 + wm + i * 16 + quad * 4 + r;  // s*2+b
                    const int s = rowg >> 1, b = rowg & 1;
                    dst[((b * NH + h) * HD + d) * S_LEN + s] = f2b(acc[i][j][r] + bv_);
                }
            }
        }
    } else {
        const float scale = (mat == 0) ? QSCALE : 1.0f;
#pragma unroll
        for (int i = 0; i < 4; i++) {
#pragma unroll
            for (int jp = 0; jp < 2; jp++) {
                const int c1 = nn0 + wn + jp * 16 + qm;        // col of low half
                const float b1 = bias[c1], b2 = bias[c1 + 32];
                const int h = c1 >> 6;
                const int d1 = c1 & 63;                        // = jp*16+qm, < 32
#pragma unroll
                for (int r = 0; r < 4; r++) {
                    const int rowg = m0 + wm + i * 16 + quad * 4 + r;  // s*2+b
                    const int s = rowg >> 1, b = rowg & 1;
                    const float cs = rtab[s * 64 + d1];
                    const float sn = rtab[s * 64 + d1 + 32];
                    const float x1 = (acc[i][jp][r] + b1) * scale;
                    const float x2 = (acc[i][jp + 2][r] + b2) * scale;
                    unsigned short* base = &dst[((b * NH + h) * S_LEN + s) * HD];
                    base[d1]      = f2b(x1 * cs - x2 * sn);
                    base[d1 + 32] = f2b(x2 * cs + x1 * sn);
                }
            }
        }
    }
}

// ---------------------------------------------------------------------------
// QKV projection, plan A (frozen r10/r11): global_load_lds staging,
// unpadded LDS [128][64] with XOR column swizzle.
// ---------------------------------------------------------------------------
__global__ __launch_bounds__(256) void qkv_gemm_gl(
    const unsigned short* __restrict__ Xb,
    const unsigned short* __restrict__ Wb,   // Wq|Wk|Wv bf16, 1M elems each
    const float* __restrict__ bq, const float* __restrict__ bk,
    const float* __restrict__ bv,
    const float* __restrict__ rtab,
    unsigned short* __restrict__ Qh, unsigned short* __restrict__ Kh,
    unsigned short* __restrict__ Vt)
{
    __shared__ unsigned short At[128 * 64];   // 16 KB, unpadded
    __shared__ unsigned short Bt[128 * 64];   // 16 KB, unpadded

    const int tid  = threadIdx.x;
    const int wave = tid >> 6, lane = tid & 63;
    const int wm = (wave >> 1) * 64, wn = (wave & 1) * 64;
    const int qm = lane & 15, quad = lane >> 4;

    const int m0  = blockIdx.x * 128;
    const int n0g = blockIdx.y * 128;
    const int mat = n0g >> 10;              // 0=q 1=k 2=v
    const int nn0 = n0g & 1023;

    const unsigned short* W = Wb + (size_t)mat * 1048576;
    const float* bias = (mat == 0) ? bq : (mat == 1) ? bk : bv;
    unsigned short* dst = (mat == 0) ? Qh : (mat == 1) ? Kh : Vt;

    floatx4 acc[4][4] = {};

    const int xs = qm & 7;   // reader xor term: row&7 == qm&7 for frag rows

    for (int k0 = 0; k0 < EMB; k0 += 64) {
#pragma unroll
        for (int c = 0; c < 4; c++) {
            const int e   = (c * 256 + tid) * 8;          // LDS elem offset
            const int row = e >> 6;                       // 0..127
            const int gcol = (((e >> 3) & 7) ^ (row & 7)) * 8;
            g2l16(&Xb[(m0 + row) * EMB + k0 + gcol], &At[e]);
            g2l16(&W[(nn0 + row) * EMB + k0 + gcol], &Bt[e]);
        }
        __syncthreads();

#pragma unroll
        for (int kk = 0; kk < 2; kk++) {
            shortx8 a[4], b[4];
#pragma unroll
            for (int i = 0; i < 4; i++)
                a[i] = *(shortx8*)&At[(wm + i * 16 + qm) * 64 + (((kk * 4 + quad) ^ xs) * 8)];
#pragma unroll
            for (int j = 0; j < 4; j++)
                b[j] = *(shortx8*)&Bt[(wn + j * 16 + qm) * 64 + (((kk * 4 + quad) ^ xs) * 8)];
#pragma unroll
            for (int i = 0; i < 4; i++)
#pragma unroll
                for (int j = 0; j < 4; j++)
                    acc[i][j] = __builtin_amdgcn_mfma_f32_16x16x32_bf16(a[i], b[j], acc[i][j], 0, 0, 0);
        }
        __syncthreads();
    }

    qkv_epilogue(acc, mat, m0, nn0, wm, wn, qm, quad, bias, rtab, dst);
}

// ---------------------------------------------------------------------------
// QKV projection, plan B fallback (r7 structure, padded LDS, in-kernel X cvt).
// ---------------------------------------------------------------------------
#define LDB 72

__global__ __launch_bounds__(256) void qkv_gemm_fb(
    const float* __restrict__ X,
    const unsigned short* __restrict__ Wb,
    const float* __restrict__ bq, const float* __restrict__ bk,
    const float* __restrict__ bv,
    const float* __restrict__ rtab,
    unsigned short* __restrict__ Qh, unsigned short* __restrict__ Kh,
    unsigned short* __restrict__ Vt)
{
    __shared__ unsigned short At[128 * LDB];
    __shared__ unsigned short Bt[128 * LDB];

    const int tid  = threadIdx.x;
    const int wave = tid >> 6, lane = tid & 63;
    const int wm = (wave >> 1) * 64, wn = (wave & 1) * 64;
    const int qm = lane & 15, quad = lane >> 4;

    const int m0  = blockIdx.x * 128;
    const int n0g = blockIdx.y * 128;
    const int mat = n0g >> 10;
    const int nn0 = n0g & 1023;

    const unsigned short* W = Wb + (size_t)mat * 1048576;
    const float* bias = (mat == 0) ? bq : (mat == 1) ? bk : bv;
    unsigned short* dst = (mat == 0) ? Qh : (mat == 1) ? Kh : Vt;

    const int r0 = tid >> 3;
    const int ko = (tid & 7) * 8;

    floatx4 acc[4][4] = {};

    for (int k0 = 0; k0 < EMB; k0 += 64) {
#pragma unroll
        for (int c = 0; c < 4; c++) {
            const int row = r0 + 32 * c;
            *(shortx8*)&At[row * LDB + ko] = cvt8(&X[(m0 + row) * EMB + k0 + ko]);
            *(shortx8*)&Bt[row * LDB + ko] = *(const shortx8*)&W[(nn0 + row) * EMB + k0 + ko];
        }
        __syncthreads();

#pragma unroll
        for (int kk = 0; kk < 2; kk++) {
            shortx8 a[4], b[4];
#pragma unroll
            for (int i = 0; i < 4; i++)
                a[i] = *(shortx8*)&At[(wm + i * 16 + qm) * LDB + kk * 32 + quad * 8];
#pragma unroll
            for (int j = 0; j < 4; j++)
                b[j] = *(shortx8*)&Bt[(wn + j * 16 + qm) * LDB + kk * 32 + quad * 8];
#pragma unroll
            for (int i = 0; i < 4; i++)
#pragma unroll
                for (int j = 0; j < 4; j++)
                    acc[i][j] = __builtin_amdgcn_mfma_f32_16x16x32_bf16(a[i], b[j], acc[i][j], 0, 0, 0);
        }
        __syncthreads();
    }

    qkv_epilogue(acc, mat, m0, nn0, wm, wn, qm, quad, bias, rtab, dst);
}

// ---------------------------------------------------------------------------
// Flash attention (r11 exact, the 72 us known-good): 8 waves x 16 q-rows,
// K-tile 128 (16 iters), 512 blocks = 2/CU x 8 waves = 16 waves/CU.
// exp2 softmax (log2e folded into Q scale), deferred row-sum.
// O overwrites this block's own Q rows in-place.
// ---------------------------------------------------------------------------
#define LDK 72    // K rows: 64 d + pad
#define LDV 136   // VT/P rows: 128 s + pad

__global__ __launch_bounds__(512) void attn_kernel(
    unsigned short* Qh,               // read, then overwritten in-place with O
    const unsigned short* __restrict__ Kh,
    const unsigned short* __restrict__ Vt)
{
    __shared__ unsigned short ldsK[128 * LDK];      // 18432 B
    __shared__ unsigned short ldsVT[64 * LDV];      // 17408 B
    __shared__ unsigned short ldsP[8 * 16 * LDV];   // 34816 B

    const int tid  = threadIdx.x;
    const int wave = tid >> 6, lane = tid & 63;     // wave 0..7
    const int qm = lane & 15, quad = lane >> 4;
    const int bh = blockIdx.y;
    const int qrow = blockIdx.x * 128 + wave * 16;

    unsigned short* Qp = Qh + bh * HEAD_STRIDE;
    const unsigned short* Kp = Kh + bh * HEAD_STRIDE;
    const unsigned short* Vp = Vt + bh * HEAD_STRIDE;   // [d][s]

    const shortx8 aq0 = *(const shortx8*)&Qp[(qrow + qm) * HD + quad * 8];
    const shortx8 aq1 = *(const shortx8*)&Qp[(qrow + qm) * HD + 32 + quad * 8];

    floatx4 od[4] = {};
    float l_part[4] = {0.f, 0.f, 0.f, 0.f};

    unsigned short* myP = &ldsP[wave * 16 * LDV];

    const int kr = tid >> 3;        // 0..63
    const int ko = (tid & 7) * 8;   // 0..56
    const int vr = tid >> 4;        // 0..31
    const int vo = (tid & 15) * 8;  // 0..120

    for (int kt = 0; kt < S_LEN / 128; kt++) {
        const int kbase = kt * 128;
#pragma unroll
        for (int c = 0; c < 2; c++) {
            *(shortx8*)&ldsK[(kr + 64 * c) * LDK + ko] =
                *(const shortx8*)&Kp[(kbase + kr + 64 * c) * HD + ko];
            *(shortx8*)&ldsVT[(vr + 32 * c) * LDV + vo] =
                *(const shortx8*)&Vp[(vr + 32 * c) * S_LEN + kbase + vo];
        }
        __syncthreads();

        // S = Q K^T (16 x 128 per wave)
        floatx4 sc[8];
#pragma unroll
        for (int nt = 0; nt < 8; nt++) {
            const int krow = nt * 16 + qm;
            const shortx8 b0 = *(shortx8*)&ldsK[krow * LDK + quad * 8];
            const shortx8 b1 = *(shortx8*)&ldsK[krow * LDK + 32 + quad * 8];
            floatx4 a = {};
            a = __builtin_amdgcn_mfma_f32_16x16x32_bf16(aq0, b0, a, 0, 0, 0);
            a = __builtin_amdgcn_mfma_f32_16x16x32_bf16(aq1, b1, a, 0, 0, 0);
            sc[nt] = a;
        }

        // p = exp2(s) (log2e pre-folded); per-lane row partial sums
#pragma unroll
        for (int nt = 0; nt < 8; nt++)
#pragma unroll
            for (int r = 0; r < 4; r++)
                sc[nt][r] = EXP2(sc[nt][r]);
#pragma unroll
        for (int r = 0; r < 4; r++) {
            float t0 = (sc[0][r] + sc[1][r]) + (sc[2][r] + sc[3][r]);
            float t1 = (sc[4][r] + sc[5][r]) + (sc[6][r] + sc[7][r]);
            l_part[r] += t0 + t1;
        }

        // P: C-layout regs -> wave-private LDS (cheap round) -> A-layout frags
#pragma unroll
        for (int nt = 0; nt < 8; nt++)
#pragma unroll
            for (int r = 0; r < 4; r++)
                myP[(quad * 4 + r) * LDV + nt * 16 + qm] = f2b_fast(sc[nt][r]);

        shortx8 ap[4];
#pragma unroll
        for (int kc = 0; kc < 4; kc++)
            ap[kc] = *(shortx8*)&myP[qm * LDV + kc * 32 + quad * 8];
#pragma unroll
        for (int dt = 0; dt < 4; dt++) {
            const int d = dt * 16 + qm;
#pragma unroll
            for (int kc = 0; kc < 4; kc++) {
                const shortx8 vb = *(shortx8*)&ldsVT[d * LDV + kc * 32 + quad * 8];
                od[dt] = __builtin_amdgcn_mfma_f32_16x16x32_bf16(ap[kc], vb, od[dt], 0, 0, 0);
            }
        }
        __syncthreads();   // all waves done with ldsK/ldsVT before restage
    }

    float inv_l[4];
#pragma unroll
    for (int r = 0; r < 4; r++) {
        float s = l_part[r];
        for (int off = 1; off < 16; off <<= 1) s += __shfl_xor(s, off, 64);
        inv_l[r] = 1.0f / s;
    }

#pragma unroll
    for (int r = 0; r < 4; r++) {
        const int rq = qrow + quad * 4 + r;
#pragma unroll
        for (int dt = 0; dt < 4; dt++) {
            const int d = dt * 16 + qm;
            Qp[rq * HD + d] = f2b(od[dt][r] * inv_l[r]);
        }
    }
}

// ---------------------------------------------------------------------------
// Output projection v2 (kept from r12, ~6 us win): out = O @ Wo^T + bo.
// 128x128 tile, BK=64 (16 iters); Wo converted fp32->bf16 during staging.
// O bf16 head-major.
// ---------------------------------------------------------------------------
__global__ __launch_bounds__(256) void out_gemm(
    const unsigned short* __restrict__ O,
    const float* __restrict__ Wo, const float* __restrict__ bo,
    float* __restrict__ out)
{
    __shared__ unsigned short At[128 * LDB];
    __shared__ unsigned short Bt[128 * LDB];

    const int tid  = threadIdx.x;
    const int wave = tid >> 6, lane = tid & 63;
    const int wm = (wave >> 1) * 64, wn = (wave & 1) * 64;
    const int qm = lane & 15, quad = lane >> 4;
    const int m0 = blockIdx.x * 128;
    const int n0 = blockIdx.y * 128;

    const int r0 = tid >> 3;          // 0..31
    const int ko = (tid & 7) * 8;     // 0..56

    floatx4 acc[4][4] = {};

    for (int k0 = 0; k0 < EMB; k0 += 64) {
        const int k = k0 + ko;
#pragma unroll
        for (int c = 0; c < 4; c++) {
            const int row = r0 + 32 * c;
            const int m = m0 + row;
            // head-major gather: 8 contiguous elems stay within one head
            *(shortx8*)&At[row * LDB + ko] =
                *(const shortx8*)&O[(((m & 1) * NH + (k >> 6)) * S_LEN + (m >> 1)) * HD + (k & 63)];
            *(shortx8*)&Bt[row * LDB + ko] = cvt8(&Wo[(n0 + row) * EMB + k]);
        }
        __syncthreads();

#pragma unroll
        for (int kk = 0; kk < 2; kk++) {
            shortx8 a[4], b[4];
#pragma unroll
            for (int i = 0; i < 4; i++)
                a[i] = *(shortx8*)&At[(wm + i * 16 + qm) * LDB + kk * 32 + quad * 8];
#pragma unroll
            for (int j = 0; j < 4; j++)
                b[j] = *(shortx8*)&Bt[(wn + j * 16 + qm) * LDB + kk * 32 + quad * 8];
#pragma unroll
            for (int i = 0; i < 4; i++)
#pragma unroll
                for (int j = 0; j < 4; j++)
                    acc[i][j] = __builtin_amdgcn_mfma_f32_16x16x32_bf16(a[i], b[j], acc[i][j], 0, 0, 0);
        }
        __syncthreads();
    }

#pragma unroll
    for (int i = 0; i < 4; i++) {
#pragma unroll
        for (int j = 0; j < 4; j++) {
            const int colg = n0 + wn + j * 16 + qm;
            const float bv_ = bo[colg];
#pragma unroll
            for (int r = 0; r < 4; r++) {
                const int rowg = m0 + wm + i * 16 + quad * 4 + r;
                out[rowg * EMB + colg] = acc[i][j][r] + bv_;
            }
        }
    }
}

// ---------------------------------------------------------------------------
extern "C" void kernel_launch(void* const* d_in, const int* in_sizes, int n_in,
                              void* d_out, int out_size, void* d_ws, size_t ws_size,
                              hipStream_t stream) {
    const float* X  = (const float*)d_in[0];
    const float* Wq = (const float*)d_in[1];
    const float* bq = (const float*)d_in[2];
    const float* Wk = (const float*)d_in[3];
    const float* bk = (const float*)d_in[4];
    const float* Wv = (const float*)d_in[5];
    const float* bv = (const float*)d_in[6];
    const float* Wo = (const float*)d_in[7];
    const float* bo = (const float*)d_in[8];
    float* out = (float*)d_out;

    unsigned short* ws = (unsigned short*)d_ws;
    unsigned short* Vt  = ws;                                  // [32][64][2048] bf16
    unsigned short* Qh  = ws + (size_t)BH * HEAD_STRIDE;       // [32][2048][64] bf16
    unsigned short* Xb  = ws + (size_t)2 * BH * HEAD_STRIDE;   // [4096][1024] bf16 (plan A)
    unsigned short* Kh  = (unsigned short*)d_out;              // [0..4M) u16 (borrowed)
    unsigned short* Wb  = (unsigned short*)d_out + 4194304;    // [4M..7M) u16: Wq|Wk|Wv bf16
    float*          Rt  = (float*)d_out + 3670016;             // [14..14.5MB): rope table

    const bool use_xb = ws_size >= (size_t)24 * 1024 * 1024;   // constant per session

    prep<<<dim3(use_xb ? 3840 : 1792), 256, 0, stream>>>(X, Wq, Wk, Wv, Xb, Wb, Rt);

    if (use_xb)
        qkv_gemm_gl<<<dim3(MROWS / 128, 3 * EMB / 128), 256, 0, stream>>>(
            Xb, Wb, bq, bk, bv, Rt, Qh, Kh, Vt);
    else
        qkv_gemm_fb<<<dim3(MROWS / 128, 3 * EMB / 128), 256, 0, stream>>>(
            X, Wb, bq, bk, bv, Rt, Qh, Kh, Vt);

    attn_kernel<<<dim3(S_LEN / 128, BH), 512, 0, stream>>>(Qh, Kh, Vt);
    out_gemm<<<dim3(MROWS / 128, EMB / 128), 256, 0, stream>>>(Qh, Wo, bo, out);
}